// Round 8
// baseline (343.776 us; speedup 1.0000x reference)
//
#include <hip/hip_runtime.h>
#include <math.h>

typedef __attribute__((ext_vector_type(8))) short short8;
typedef __attribute__((ext_vector_type(16))) float f32x16;

#define D      128
#define NSEG   128
#define NHSEG  256           // half-segs for pass 1 (13+12 tile split)
#define SEGC   800           // candidates per segment (multiple of 32)
#define NT     25            // SEGC / 32
#define TPP    5             // tiles per pass-2 work item (NT/NPART)
#define NPART  5
#define TILE_C 32
#define KTOP   10
#define CAP    128
#define DELTA  3.0f
#define NPAD   (NSEG * SEGC + 2 * TILE_C)  // +2 pad tiles for 2-deep prefetch overrun (== 102464)
#define ROWU   128           // ushorts per row (256 B, no pad; x2w lives in x2wp[])
#define TUNITS (TILE_C * 16) // 512 16B-units per tile
#define BUFU   (TUNITS * 8)  // 4096 ushorts per LDS buffer (8 KiB)
#define MQ     2048          // m (fixed by problem) — LDS list size in list_build
#define WQCAP  (NSEG * 8 * NPART)

// LDS swizzle: unit (r,kb) stored at r*16 + (kb ^ (r&7)).
// Write phase (16 lanes, one row, kb 0..15): groups kb^(r&7) span 8 quads twice = 2-way (free).
// Read phase (8 lanes, rows r..r+7, same kb): groups kb^(0..7) = 8 distinct quads (conflict-free).
__device__ __forceinline__ int swz16(int u) {
    int r = u >> 4, kb = u & 15;
    return r * 16 + (kb ^ (r & 7));
}

// ---------- helpers ----------
__device__ __forceinline__ ushort f2bf(float f) {
    uint u = __float_as_uint(f);
    uint r = (u + 0x7FFFu + ((u >> 16) & 1u)) >> 16;
    return (ushort)r;
}

__device__ __forceinline__ uint packx2(float x2w) {
    ushort h = f2bf(x2w);
    float hf = __uint_as_float(((uint)h) << 16);
    ushort lo = f2bf(x2w - hf);
    return (uint)h | ((uint)lo << 16);
}

__device__ __forceinline__ void insert10(float s, float v, float ls[KTOP], float lw[KTOP]) {
    ls[9] = s; lw[9] = v;
#pragma unroll
    for (int p = 9; p > 0; --p) {
        bool sw = ls[p] < ls[p - 1];
        float ts = sw ? ls[p - 1] : ls[p];
        float tl = sw ? ls[p]     : ls[p - 1];
        float tv = sw ? lw[p - 1] : lw[p];
        float tu = sw ? lw[p]     : lw[p - 1];
        ls[p] = ts; ls[p - 1] = tl;
        lw[p] = tv; lw[p - 1] = tu;
    }
}

__device__ __forceinline__ void insert10s(float s, float ms[KTOP]) {
    ms[9] = s;
#pragma unroll
    for (int p = 9; p > 0; --p) {
        float a = fminf(ms[p - 1], ms[p]);
        float b = fmaxf(ms[p - 1], ms[p]);
        ms[p - 1] = a; ms[p] = b;
    }
}

// ---------- fused prep: candidates (256B bf16 rows + x2wp side array), queries, cnt zero ----------
__global__ void prep_kernel(const float* __restrict__ Xt, const float* __restrict__ X,
                            const float* __restrict__ w,
                            ushort* __restrict__ Xbp, ushort* __restrict__ Xtb,
                            uint* __restrict__ x2wp,
                            float* __restrict__ x2wf, float* __restrict__ q2f,
                            int* __restrict__ cnt, int* __restrict__ wq_n,
                            int n, int m, int nblocksA) {
    if (blockIdx.x == 0 && threadIdx.x == 0) wq_n[0] = 0;
    int wave = threadIdx.x >> 6, lane = threadIdx.x & 63;
    if ((int)blockIdx.x < nblocksA) {
        int row = blockIdx.x * 4 + wave;
        if (row >= NPAD) return;
        ushort* rowp = Xbp + (size_t)row * ROWU;
        if (row < n) {
            float2 v = ((const float2*)X)[(size_t)row * 64 + lane];
            ((ushort2*)rowp)[lane] = make_ushort2(f2bf(v.x), f2bf(v.y));
            float s = v.x * v.x + v.y * v.y;
#pragma unroll
            for (int o = 32; o; o >>= 1) s += __shfl_xor(s, o, 64);
            float x2w = s - w[row];
            if (lane == 0) { x2wf[row] = x2w; x2wp[row] = packx2(x2w); }
        } else {
            ((ushort2*)rowp)[lane] = make_ushort2(0, 0);      // sentinel: zero data
            if (lane == 0) x2wp[row] = packx2(1e30f);
        }
    } else {
        int qb = blockIdx.x - nblocksA;
        int row = qb * 4 + wave;
        int tid = qb * 256 + threadIdx.x;
        if (tid < m) cnt[tid] = 0;
        if (row >= m) return;
        float2 v = ((const float2*)Xt)[(size_t)row * 64 + lane];
        ((ushort2*)Xtb)[(size_t)row * 64 + lane] = make_ushort2(f2bf(v.x), f2bf(v.y));
        float s = v.x * v.x + v.y * v.y;
#pragma unroll
        for (int o = 32; o; o >>= 1) s += __shfl_xor(s, o, 64);
        if (lane == 0) q2f[row] = s;
    }
}

__device__ __forceinline__ void emit_cand(int q, int c, int* cnt, int* buf) {
    int pos = atomicAdd(&cnt[q], 1);
    if (pos < CAP) buf[q * CAP + pos] = c;
}

// ---------- pass 1: full GEMM, per-(query, quarter-seg) stream mins ----------
// 2048 blocks = 256 half-segs x 8 query-blocks; (256,4): 4 blocks/CU — the PROVEN register
// fit. Block: 4 waves x 64 queries. Wave tile: 32 cands x 64 queries.
// NEW: 2-tile rounds with 4 LDS buffers — write tiles (2r,2r+1) into buffer-pair r&1,
// ONE __syncthreads, prefetch tiles (2r+2,2r+3), compute both 18-MFMA chains. Halves the
// per-tile barrier+drain overhead; pair rotation preserves the R2 ordering proof (round r's
// ds_reads drain via MFMA lgkmcnt before round r+1's barrier; pair p rewritten in r+2).
// Odd tail tile gets a single-tile round (quarter partitions stay disjoint -> tau sound).
// acc = q.x - 0.5*x2w  =>  s = -2*acc.
__global__ __launch_bounds__(256, 4) void nd_pass1(
        const ushort* __restrict__ Xbp, const ushort* __restrict__ Xtb,
        const uint* __restrict__ x2wp,
        float* __restrict__ minbuf, int m) {
    __shared__ __align__(16) ushort As[4 * BUFU];   // 4 x 8192 B

    const int t = threadIdx.x;
    const int l = t & 63, wv = t >> 6;
    const int half = l >> 5;
    const int hs = blockIdx.x;
    const int seg = hs >> 1, sub = hs & 1;
    const int tile0 = seg * NT + sub * 13;
    const int ntile = 13 - sub;
    const int qbase = blockIdx.y * 256 + wv * 64;
    const int q0 = qbase + (l & 31);                 // query for qsub 0 (qsub 1 -> +32)

    short8 Bf[8][2];
#pragma unroll
    for (int s = 0; s < 8; ++s)
#pragma unroll
        for (int qs = 0; qs < 2; ++qs)
            Bf[s][qs] = *(const short8*)(Xtb + (size_t)(q0 + qs * 32) * D + s * 16 + half * 8);
    short8 B8 = (short8)(short)0;
    if (l < 32) { B8[0] = (short)0xBF00; B8[1] = (short)0xBF00; }  // -0.5 at k=128,129

    float mx0 = -INFINITY, mx1 = -INFINITY;

    // staging: thread t owns global units t and 256+t (512 units/tile)
    const int u0 = t, u1 = 256 + t;
    const int L0 = swz16(u0) * 8, L1 = swz16(u1) * 8;
    const uint4* Xg = (const uint4*)Xbp;
    // per-lane swizzled read addresses (ushort index), invariant across tiles
    int raddr[8];
#pragma unroll
    for (int ks = 0; ks < 8; ++ks)
        raddr[ks] = ((l & 31) * 16 + ((2 * ks + half) ^ (l & 7))) * 8;

    auto compute_tile = [&](const ushort* Lb, uint pk) {
        f32x16 acc0 = (f32x16)0.f, acc1 = (f32x16)0.f;
#pragma unroll
        for (int ks = 0; ks < 8; ++ks) {
            short8 a = *(const short8*)&Lb[raddr[ks]];
            acc0 = __builtin_amdgcn_mfma_f32_32x32x16_bf16(a, Bf[ks][0], acc0, 0, 0, 0);
            acc1 = __builtin_amdgcn_mfma_f32_32x32x16_bf16(a, Bf[ks][1], acc1, 0, 0, 0);
        }
        // kstep 9: x2w bias from regs (only half-0 lanes' elems 0,1 hit nonzero B)
        short8 av9 = (short8)(short)0;
        av9[0] = (short)(pk & 0xffff);
        av9[1] = (short)(pk >> 16);
        acc0 = __builtin_amdgcn_mfma_f32_32x32x16_bf16(av9, B8, acc0, 0, 0, 0);
        acc1 = __builtin_amdgcn_mfma_f32_32x32x16_bf16(av9, B8, acc1, 0, 0, 0);
        float h0 = -INFINITY, h1 = -INFINITY;
#pragma unroll
        for (int r = 0; r < 16; ++r) { h0 = fmaxf(h0, acc0[r]); h1 = fmaxf(h1, acc1[r]); }
        mx0 = fmaxf(mx0, h0);
        mx1 = fmaxf(mx1, h1);
    };

    const int nr = ntile >> 1;            // full 2-tile rounds (6 for both subs)
    // prefetch tiles tile0, tile0+1
    uint4 a0 = Xg[(size_t)(tile0 + 0) * TUNITS + u0];
    uint4 a1 = Xg[(size_t)(tile0 + 0) * TUNITS + u1];
    uint4 b0 = Xg[(size_t)(tile0 + 1) * TUNITS + u0];
    uint4 b1 = Xg[(size_t)(tile0 + 1) * TUNITS + u1];
    uint pka = x2wp[(tile0 + 0) * TILE_C + (l & 31)];
    uint pkb = x2wp[(tile0 + 1) * TILE_C + (l & 31)];

    for (int r2 = 0; r2 < nr; ++r2) {
        ushort* LbA = &As[((r2 & 1) * 2 + 0) * BUFU];
        ushort* LbB = &As[((r2 & 1) * 2 + 1) * BUFU];
        *(uint4*)&LbA[L0] = a0; *(uint4*)&LbA[L1] = a1;
        *(uint4*)&LbB[L0] = b0; *(uint4*)&LbB[L1] = b1;
        __syncthreads();

        // prefetch tiles 2r+2, 2r+3 (pad tiles cover the final overrun, max tile 3201)
        const int tn = tile0 + 2 * r2 + 2;
        const uint pka_c = pka, pkb_c = pkb;
        a0 = Xg[(size_t)tn * TUNITS + u0];
        a1 = Xg[(size_t)tn * TUNITS + u1];
        b0 = Xg[(size_t)(tn + 1) * TUNITS + u0];
        b1 = Xg[(size_t)(tn + 1) * TUNITS + u1];
        pka = x2wp[tn * TILE_C + (l & 31)];
        pkb = x2wp[(tn + 1) * TILE_C + (l & 31)];

        compute_tile(LbA, pka_c);
        compute_tile(LbB, pkb_c);
    }
    if (ntile & 1) {                      // tail tile (sub=0 only): regs a* hold tile0+12
        ushort* LbA = &As[((nr & 1) * 2 + 0) * BUFU];
        *(uint4*)&LbA[L0] = a0; *(uint4*)&LbA[L1] = a1;
        __syncthreads();
        compute_tile(LbA, pka);
    }

    size_t rowi = (size_t)(hs * 2 + half) * m;
    minbuf[rowi + q0]      = -2.f * mx0;
    minbuf[rowi + q0 + 32] = -2.f * mx1;
}

// ---------- tau: 10th smallest of 4*NSEG stream-mins per query, + margin ----------
// Soundness is partition-granularity-independent: the 10 smallest partition-mins are the
// scores of 10 distinct candidates, so tau >= 10th-best bf16 score; DELTA covers bf16<->fp32.
__global__ void tau_kernel(const float* __restrict__ minbuf, float* __restrict__ tau, int m) {
    __shared__ float sh[64 * 40];
    const int qi = threadIdx.x & 63, part = threadIdx.x >> 6;
    const int q = blockIdx.x * 64 + qi;
    float ms[KTOP];
#pragma unroll
    for (int e = 0; e < KTOP; ++e) ms[e] = INFINITY;
#pragma unroll 4
    for (int i = 0; i < 128; ++i) {
        float v = minbuf[(size_t)(part * 128 + i) * m + q];
        if (v < ms[9]) insert10s(v, ms);
    }
#pragma unroll
    for (int e = 0; e < KTOP; ++e) sh[qi * 40 + part * 10 + e] = ms[e];
    __syncthreads();
    if (threadIdx.x < 64) {
        const int qq = blockIdx.x * 64 + threadIdx.x;
        float fs[KTOP];
#pragma unroll
        for (int e = 0; e < KTOP; ++e) fs[e] = INFINITY;
        for (int x = 0; x < 40; ++x) {
            float v = sh[threadIdx.x * 40 + x];
            if (v < fs[9]) insert10s(v, fs);
        }
        tau[qq] = fs[9] + DELTA;
    }
}

// ---------- list build: per-seg qualifying queries + flat work queue ----------
// Seg s can emit for query q iff min of its 4 quarter-mins <= tau[q]; exact equivalence
// with pass-2's emission test (same acc values, *-2 / *0.5 are exact).
__global__ void list_build(const float* __restrict__ minbuf, const float* __restrict__ tau,
                           int* __restrict__ qlist, int* __restrict__ wq,
                           int* __restrict__ wq_n, int m) {
    __shared__ int lq[MQ];
    __shared__ int lcnt;
    const int s = blockIdx.x, tid = threadIdx.x;
    if (tid == 0) lcnt = 0;
    __syncthreads();
    const float* r0 = minbuf + (size_t)(4 * s) * m;
    const float* r1 = minbuf + (size_t)(4 * s + 1) * m;
    const float* r2 = minbuf + (size_t)(4 * s + 2) * m;
    const float* r3 = minbuf + (size_t)(4 * s + 3) * m;
    for (int q = tid; q < m; q += 256) {
        float v = fminf(fminf(r0[q], r1[q]), fminf(r2[q], r3[q]));
        if (v <= tau[q]) { int p = atomicAdd(&lcnt, 1); lq[p] = q; }
    }
    __syncthreads();
    const int c = lcnt;
    const int padded = (c + 255) & ~255;
    for (int i = c + tid; i < padded; i += 256) lq[i] = -1;   // sentinel queries
    __syncthreads();
    for (int i = tid; i < padded; i += 256) qlist[(size_t)s * MQ + i] = lq[i];
    if (tid == 0 && c > 0) {
        const int nqc = padded >> 8;
        int base = atomicAdd(wq_n, nqc * NPART);
        for (int qc = 0; qc < nqc; ++qc)
            for (int p = 0; p < NPART; ++p)
                wq[base++] = (s << 6) | (qc << 3) | p;
    }
}

// ---------- pass 2: sparse candidate emission over the work queue ----------
__global__ __launch_bounds__(256, 4) void nd_pass2(
        const ushort* __restrict__ Xbp, const ushort* __restrict__ Xtb,
        const uint* __restrict__ x2wp, const float* __restrict__ tau,
        int* __restrict__ cnt, int* __restrict__ buf,
        const int* __restrict__ qlist, const int* __restrict__ wq,
        const int* __restrict__ wq_n, int m) {
    __shared__ __align__(16) ushort As[2 * BUFU];

    const int t = threadIdx.x;
    const int l = t & 63, wv = t >> 6;
    const int half = l >> 5;
    const int u0 = t, u1 = 256 + t;
    const int L0 = swz16(u0) * 8, L1 = swz16(u1) * 8;
    const uint4* Xg = (const uint4*)Xbp;
    int raddr[8];
#pragma unroll
    for (int ks = 0; ks < 8; ++ks)
        raddr[ks] = ((l & 31) * 16 + ((2 * ks + half) ^ (l & 7))) * 8;
    const int T = wq_n[0];

    for (int w = blockIdx.x; w < T; w += gridDim.x) {
        const int it = wq[w];
        const int s = it >> 6, qc = (it >> 3) & 7, part = it & 7;
        const int t0 = s * NT + part * TPP;
        const int lbase = s * MQ + qc * 256 + wv * 64 + (l & 31);
        const int qi0 = qlist[lbase], qi1 = qlist[lbase + 32];
        const int q0e = qi0 < 0 ? 0 : qi0, q1e = qi1 < 0 ? 0 : qi1;

        short8 Bf[8][2];
#pragma unroll
        for (int sk = 0; sk < 8; ++sk) {
            Bf[sk][0] = *(const short8*)(Xtb + (size_t)q0e * D + sk * 16 + half * 8);
            Bf[sk][1] = *(const short8*)(Xtb + (size_t)q1e * D + sk * 16 + half * 8);
        }
        short8 B8 = (short8)(short)0;
        if (l < 32) { B8[0] = (short)0xBF00; B8[1] = (short)0xBF00; }
        const float tp0 = (qi0 < 0) ? INFINITY : (-0.5f * tau[qi0]);
        const float tp1 = (qi1 < 0) ? INFINITY : (-0.5f * tau[qi1]);

        uint4 r0 = Xg[(size_t)t0 * TUNITS + u0];
        uint4 r1 = Xg[(size_t)t0 * TUNITS + u1];
        uint pkc = x2wp[t0 * TILE_C + (l & 31)];

        for (int t2 = t0; t2 < t0 + TPP; ++t2) {
            ushort* Lb = &As[(t2 & 1) * BUFU];
            *(uint4*)&Lb[L0] = r0;
            *(uint4*)&Lb[L1] = r1;
            __syncthreads();

            const size_t gb = (size_t)(t2 + 1) * TUNITS;   // overrun covered by pad tiles
            r0 = Xg[gb + u0];
            r1 = Xg[gb + u1];
            uint pkn = x2wp[(t2 + 1) * TILE_C + (l & 31)];

            f32x16 acc0 = (f32x16)0.f, acc1 = (f32x16)0.f;
#pragma unroll
            for (int ks = 0; ks < 8; ++ks) {
                short8 a = *(const short8*)&Lb[raddr[ks]];
                acc0 = __builtin_amdgcn_mfma_f32_32x32x16_bf16(a, Bf[ks][0], acc0, 0, 0, 0);
                acc1 = __builtin_amdgcn_mfma_f32_32x32x16_bf16(a, Bf[ks][1], acc1, 0, 0, 0);
            }
            short8 av9 = (short8)(short)0;
            av9[0] = (short)(pkc & 0xffff);
            av9[1] = (short)(pkc >> 16);
            acc0 = __builtin_amdgcn_mfma_f32_32x32x16_bf16(av9, B8, acc0, 0, 0, 0);
            acc1 = __builtin_amdgcn_mfma_f32_32x32x16_bf16(av9, B8, acc1, 0, 0, 0);
            pkc = pkn;

            float h0 = -INFINITY, h1 = -INFINITY;
#pragma unroll
            for (int r = 0; r < 16; ++r) { h0 = fmaxf(h0, acc0[r]); h1 = fmaxf(h1, acc1[r]); }
            const int base = t2 * TILE_C;
            if (__any(h0 >= tp0)) {
#pragma unroll
                for (int r = 0; r < 16; ++r)
                    if (acc0[r] >= tp0) emit_cand(qi0, base + (r & 3) + 8 * (r >> 2) + 4 * half, cnt, buf);
            }
            if (__any(h1 >= tp1)) {
#pragma unroll
                for (int r = 0; r < 16; ++r)
                    if (acc1[r] >= tp1) emit_cand(qi1, base + (r & 3) + 8 * (r >> 2) + 4 * half, cnt, buf);
            }
        }
        __syncthreads();   // item boundary: next item's first LDS write vs this item's last reads
    }
}

// ---------- exact fp32 rescore ----------
__global__ void rescore_kernel(const float* __restrict__ Xtf, const float* __restrict__ Xf,
                               const float* __restrict__ w, const float* __restrict__ x2wf,
                               const float* __restrict__ q2f, const int* __restrict__ cnt,
                               const int* __restrict__ buf, float* __restrict__ out, int m) {
    __shared__ float sS[CAP], sW[CAP];
    const int q = blockIdx.x, l = threadIdx.x;
    const int c = min(cnt[q], CAP);
    const bool v0 = l < c, v1 = l + 64 < c;
    const int j0 = v0 ? buf[q * CAP + l] : 0;
    const int j1 = v1 ? buf[q * CAP + l + 64] : 0;
    const float4* Q4 = (const float4*)Xtf + (size_t)q * 32;
    const float4* A4 = (const float4*)Xf + (size_t)j0 * 32;
    const float4* B4 = (const float4*)Xf + (size_t)j1 * 32;
    float acc0 = 0.f, acc1 = 0.f;
#pragma unroll 8
    for (int d = 0; d < 32; ++d) {
        float4 qv = Q4[d];
        float4 a = A4[d], b = B4[d];
        acc0 = fmaf(qv.x, a.x, fmaf(qv.y, a.y, fmaf(qv.z, a.z, fmaf(qv.w, a.w, acc0))));
        acc1 = fmaf(qv.x, b.x, fmaf(qv.y, b.y, fmaf(qv.z, b.z, fmaf(qv.w, b.w, acc1))));
    }
    sS[l]      = v0 ? (x2wf[j0] - 2.f * acc0) : INFINITY;
    sW[l]      = v0 ? w[j0] : 0.f;
    sS[l + 64] = v1 ? (x2wf[j1] - 2.f * acc1) : INFINITY;
    sW[l + 64] = v1 ? w[j1] : 0.f;
    __syncthreads();
    if (l == 0) {
        float ls[KTOP], lw[KTOP];
#pragma unroll
        for (int e = 0; e < KTOP; ++e) { ls[e] = INFINITY; lw[e] = 0.f; }
        for (int i = 0; i < c; ++i)
            if (sS[i] < ls[9]) insert10(sS[i], sW[i], ls, lw);
        float q2v = q2f[q];
        float mxv = -INFINITY;
#pragma unroll
        for (int e = 0; e < KTOP; ++e) {
            if (ls[e] < 1e30f) {
                float d2 = fmaxf(q2v + ls[e] + lw[e], 0.f);
                mxv = fmaxf(mxv, lw[e] - sqrtf(d2));
            }
        }
        out[q] = mxv;
    }
}

// ---------- launch ----------
extern "C" void kernel_launch(void* const* d_in, const int* in_sizes, int n_in,
                              void* d_out, int out_size, void* d_ws, size_t ws_size,
                              hipStream_t stream) {
    const float* Xt = (const float*)d_in[0];
    const float* X  = (const float*)d_in[1];
    const float* w  = (const float*)d_in[2];
    const int m = in_sizes[0] / D;   // 2048
    const int n = in_sizes[1] / D;   // 100000

    auto align256 = [](size_t x) { return (x + 255) & ~(size_t)255; };
    char* p = (char*)d_ws;
    ushort* Xbp  = (ushort*)p;  p += align256((size_t)NPAD * ROWU * 2);     // ~26.2 MB
    ushort* Xtb  = (ushort*)p;  p += align256((size_t)m * D * 2);
    uint*   x2wp = (uint*)p;    p += align256((size_t)NPAD * 4);
    float*  x2wf = (float*)p;   p += align256((size_t)n * 4);
    float*  q2f  = (float*)p;   p += align256((size_t)m * 4);
    float*  minb = (float*)p;   p += align256((size_t)4 * NSEG * m * 4);    // 4 MB
    float*  tau  = (float*)p;   p += align256((size_t)m * 4);
    int*    cnt  = (int*)p;     p += align256((size_t)m * 4);
    int*    buf  = (int*)p;     p += align256((size_t)m * CAP * 4);
    int*    qlist= (int*)p;     p += align256((size_t)NSEG * MQ * 4);       // 1 MB
    int*    wq   = (int*)p;     p += align256((size_t)WQCAP * 4);
    int*    wq_n = (int*)p;     p += align256((size_t)256);

    const int nblocksA = (NPAD + 3) / 4;
    const int nblocksB = (m + 3) / 4;
    prep_kernel<<<nblocksA + nblocksB, 256, 0, stream>>>(Xt, X, w, Xbp, Xtb, x2wp, x2wf, q2f,
                                                         cnt, wq_n, n, m, nblocksA);

    dim3 grid1(NHSEG, m / 256);
    nd_pass1<<<grid1, 256, 0, stream>>>(Xbp, Xtb, x2wp, minb, m);
    tau_kernel<<<m / 64, 256, 0, stream>>>(minb, tau, m);
    list_build<<<NSEG, 256, 0, stream>>>(minb, tau, qlist, wq, wq_n, m);
    nd_pass2<<<1024, 256, 0, stream>>>(Xbp, Xtb, x2wp, tau, cnt, buf, qlist, wq, wq_n, m);
    rescore_kernel<<<m, 64, 0, stream>>>(Xt, X, w, x2wf, q2f, cnt, buf, (float*)d_out, m);
}

// Round 9
// 318.974 us; speedup vs baseline: 1.0778x; 1.0778x over previous
//
#include <hip/hip_runtime.h>
#include <math.h>

typedef __attribute__((ext_vector_type(8))) short short8;
typedef __attribute__((ext_vector_type(16))) float f32x16;

#define D      128
#define NSEG   128
#define NHSEG  256           // half-segs for pass 1 (13+12 tile split)
#define SEGC   800           // candidates per segment (multiple of 32)
#define NT     25            // SEGC / 32
#define TPP    5             // tiles per pass-2 work item (NT/NPART)
#define NPART  5
#define TILE_C 32
#define KTOP   10
#define CAP    128
#define DELTA  3.0f
#define NPAD   (NSEG * SEGC + 2 * TILE_C)  // +2 pad tiles for 2-deep prefetch overrun (== 102464)
#define ROWU   128           // ushorts per row (256 B, no pad; x2w lives in x2wp[])
#define TUNITS (TILE_C * 16) // 512 16B-units per tile
#define BUFU   (TUNITS * 8)  // 4096 ushorts per LDS buffer (8 KiB)
#define MQ     2048          // m (fixed by problem) — LDS list size in list_build
#define WQCAP  (NSEG * 8 * NPART)

// LDS swizzle: unit (r,kb) stored at r*16 + (kb ^ (r&7)); involution (apply twice = id).
// With global_load_lds (linear LDS dest), we PRE-SWIZZLE the per-lane global source:
// LDS[s] = global[swz16(s)], and the compute read at swz16(u) then yields global[u].
__device__ __forceinline__ int swz16(int u) {
    int r = u >> 4, kb = u & 15;
    return r * 16 + (kb ^ (r & 7));
}

__device__ __forceinline__ void gl_lds16(const ushort* g, ushort* lds) {
    __builtin_amdgcn_global_load_lds(
        (const __attribute__((address_space(1))) unsigned int*)g,
        (__attribute__((address_space(3))) unsigned int*)lds, 16, 0, 0);
}

// ---------- helpers ----------
__device__ __forceinline__ ushort f2bf(float f) {
    uint u = __float_as_uint(f);
    uint r = (u + 0x7FFFu + ((u >> 16) & 1u)) >> 16;
    return (ushort)r;
}

__device__ __forceinline__ uint packx2(float x2w) {
    ushort h = f2bf(x2w);
    float hf = __uint_as_float(((uint)h) << 16);
    ushort lo = f2bf(x2w - hf);
    return (uint)h | ((uint)lo << 16);
}

__device__ __forceinline__ void insert10(float s, float v, float ls[KTOP], float lw[KTOP]) {
    ls[9] = s; lw[9] = v;
#pragma unroll
    for (int p = 9; p > 0; --p) {
        bool sw = ls[p] < ls[p - 1];
        float ts = sw ? ls[p - 1] : ls[p];
        float tl = sw ? ls[p]     : ls[p - 1];
        float tv = sw ? lw[p - 1] : lw[p];
        float tu = sw ? lw[p]     : lw[p - 1];
        ls[p] = ts; ls[p - 1] = tl;
        lw[p] = tv; lw[p - 1] = tu;
    }
}

__device__ __forceinline__ void insert10s(float s, float ms[KTOP]) {
    ms[9] = s;
#pragma unroll
    for (int p = 9; p > 0; --p) {
        float a = fminf(ms[p - 1], ms[p]);
        float b = fmaxf(ms[p - 1], ms[p]);
        ms[p - 1] = a; ms[p] = b;
    }
}

// ---------- fused prep: candidates (256B bf16 rows + x2wp side array), queries, cnt zero ----------
__global__ void prep_kernel(const float* __restrict__ Xt, const float* __restrict__ X,
                            const float* __restrict__ w,
                            ushort* __restrict__ Xbp, ushort* __restrict__ Xtb,
                            uint* __restrict__ x2wp,
                            float* __restrict__ x2wf, float* __restrict__ q2f,
                            int* __restrict__ cnt, int* __restrict__ wq_n,
                            int n, int m, int nblocksA) {
    if (blockIdx.x == 0 && threadIdx.x == 0) wq_n[0] = 0;
    int wave = threadIdx.x >> 6, lane = threadIdx.x & 63;
    if ((int)blockIdx.x < nblocksA) {
        int row = blockIdx.x * 4 + wave;
        if (row >= NPAD) return;
        ushort* rowp = Xbp + (size_t)row * ROWU;
        if (row < n) {
            float2 v = ((const float2*)X)[(size_t)row * 64 + lane];
            ((ushort2*)rowp)[lane] = make_ushort2(f2bf(v.x), f2bf(v.y));
            float s = v.x * v.x + v.y * v.y;
#pragma unroll
            for (int o = 32; o; o >>= 1) s += __shfl_xor(s, o, 64);
            float x2w = s - w[row];
            if (lane == 0) { x2wf[row] = x2w; x2wp[row] = packx2(x2w); }
        } else {
            ((ushort2*)rowp)[lane] = make_ushort2(0, 0);      // sentinel: zero data
            if (lane == 0) x2wp[row] = packx2(1e30f);
        }
    } else {
        int qb = blockIdx.x - nblocksA;
        int row = qb * 4 + wave;
        int tid = qb * 256 + threadIdx.x;
        if (tid < m) cnt[tid] = 0;
        if (row >= m) return;
        float2 v = ((const float2*)Xt)[(size_t)row * 64 + lane];
        ((ushort2*)Xtb)[(size_t)row * 64 + lane] = make_ushort2(f2bf(v.x), f2bf(v.y));
        float s = v.x * v.x + v.y * v.y;
#pragma unroll
        for (int o = 32; o; o >>= 1) s += __shfl_xor(s, o, 64);
        if (lane == 0) q2f[row] = s;
    }
}

__device__ __forceinline__ void emit_cand(int q, int c, int* cnt, int* buf) {
    int pos = atomicAdd(&cnt[q], 1);
    if (pos < CAP) buf[q * CAP + pos] = c;
}

// ---------- pass 1: full GEMM, per-(query, quarter-seg) stream mins ----------
// 2048 blocks = 256 half-segs x 8 query-blocks; (256,4): 4 blocks/CU.
// 2-tile rounds, 4 LDS buffers (32KB/block), ONE barrier per 2 tiles.
// Staging via global_load_lds width=16 (NO staging VGPRs, NO ds_writes): per wave, 2 calls
// per tile cover 128 linear LDS units; per-lane global source pre-swizzled with swz16.
// Hazard proof: pair (r+1)&1 last read in round r-1; every wave passed round r-1's end
// barrier (after its reads) before any wave issues round r's STAGE. Compiler's vmcnt(0)
// drain before each s_barrier completes the load->read handoff.
// acc = q.x - 0.5*x2w  =>  s = -2*acc.
#define STAGE1(T, buf) do {                                                          \
    const ushort* gA_ = Xbp + ((size_t)(T) * TUNITS + g0u) * 8;                      \
    const ushort* gB_ = Xbp + ((size_t)(T) * TUNITS + g1u) * 8;                      \
    gl_lds16(gA_, &As[(size_t)(buf) * BUFU + (size_t)(wv * 128) * 8]);               \
    gl_lds16(gB_, &As[(size_t)(buf) * BUFU + (size_t)(wv * 128 + 64) * 8]);          \
} while (0)

#define CTILE1(buf, pk) do {                                                         \
    const char* Lc_ = (const char*)&As[(size_t)(buf) * BUFU];                        \
    f32x16 acc0 = (f32x16)0.f, acc1 = (f32x16)0.f;                                   \
    _Pragma("unroll")                                                                \
    for (int ks = 0; ks < 8; ++ks) {                                                 \
        short8 a = *(const short8*)(Lc_ + rbase + ((ks << 5) ^ hx16));               \
        acc0 = __builtin_amdgcn_mfma_f32_32x32x16_bf16(a, Bf[ks][0], acc0, 0, 0, 0); \
        acc1 = __builtin_amdgcn_mfma_f32_32x32x16_bf16(a, Bf[ks][1], acc1, 0, 0, 0); \
    }                                                                                \
    short8 av9 = (short8)(short)0;                                                   \
    av9[0] = (short)((pk) & 0xffff);                                                 \
    av9[1] = (short)((pk) >> 16);                                                    \
    acc0 = __builtin_amdgcn_mfma_f32_32x32x16_bf16(av9, B8, acc0, 0, 0, 0);          \
    acc1 = __builtin_amdgcn_mfma_f32_32x32x16_bf16(av9, B8, acc1, 0, 0, 0);          \
    float h0 = -INFINITY, h1 = -INFINITY;                                            \
    _Pragma("unroll")                                                                \
    for (int r = 0; r < 16; ++r) { h0 = fmaxf(h0, acc0[r]); h1 = fmaxf(h1, acc1[r]); } \
    mx0 = fmaxf(mx0, h0); mx1 = fmaxf(mx1, h1);                                      \
} while (0)

__global__ __launch_bounds__(256, 4) void nd_pass1(
        const ushort* __restrict__ Xbp, const ushort* __restrict__ Xtb,
        const uint* __restrict__ x2wp,
        float* __restrict__ minbuf, int m) {
    __shared__ __align__(16) ushort As[4 * BUFU];   // 4 x 8192 B

    const int t = threadIdx.x;
    const int l = t & 63, wv = t >> 6;
    const int half = l >> 5;
    const int hs = blockIdx.x;
    const int seg = hs >> 1, sub = hs & 1;
    const int tile0 = seg * NT + sub * 13;
    const int ntile = 13 - sub;
    const int qbase = blockIdx.y * 256 + wv * 64;
    const int q0 = qbase + (l & 31);                 // query for qsub 0 (qsub 1 -> +32)

    short8 Bf[8][2];
#pragma unroll
    for (int s = 0; s < 8; ++s)
#pragma unroll
        for (int qs = 0; qs < 2; ++qs)
            Bf[s][qs] = *(const short8*)(Xtb + (size_t)(q0 + qs * 32) * D + s * 16 + half * 8);
    short8 B8 = (short8)(short)0;
    if (l < 32) { B8[0] = (short)0xBF00; B8[1] = (short)0xBF00; }  // -0.5 at k=128,129

    float mx0 = -INFINITY, mx1 = -INFINITY;

    // staging source units (pre-swizzled global), loop-invariant per lane
    const int g0u = swz16(wv * 128 + l);
    const int g1u = swz16(wv * 128 + 64 + l);
    // compute-read address algebra: byte = rbase + ((ks<<5) ^ hx16)
    // (v = (2ks+half)^(l&7); v*16 = (ks<<5) ^ ((half^(l&7))<<4) since shifts distribute over XOR)
    const int rbase = (l & 31) * 256;
    const int hx16 = (half ^ (l & 7)) << 4;

    // prologue: stage tiles 0,1 into pair 0
    STAGE1(tile0 + 0, 0);
    STAGE1(tile0 + 1, 1);
    __syncthreads();

    const int nr = ntile >> 1;            // 6 full rounds for both subs
    for (int r2 = 0; r2 < nr; ++r2) {
        const int pair = (r2 & 1) * 2;
        const int npair = 2 - pair;
        const int tn = tile0 + 2 * r2;
        // prefetch next round's tiles (pad tiles cover the final overrun, max tile 3201)
        STAGE1(tn + 2, npair + 0);
        STAGE1(tn + 3, npair + 1);
        const uint pka = x2wp[tn * TILE_C + (l & 31)];
        const uint pkb = x2wp[(tn + 1) * TILE_C + (l & 31)];
        CTILE1(pair + 0, pka);
        CTILE1(pair + 1, pkb);
        __syncthreads();
    }
    if (ntile & 1) {                      // tail tile tile0+12 (sub=0): staged in round nr-1
        const uint pka = x2wp[(tile0 + 2 * nr) * TILE_C + (l & 31)];
        CTILE1((nr & 1) * 2, pka);
    }

    size_t rowi = (size_t)(hs * 2 + half) * m;
    minbuf[rowi + q0]      = -2.f * mx0;
    minbuf[rowi + q0 + 32] = -2.f * mx1;
}
#undef STAGE1
#undef CTILE1

// ---------- tau: 10th smallest of 4*NSEG stream-mins per query, + margin ----------
// Soundness is partition-granularity-independent: the 10 smallest partition-mins are the
// scores of 10 distinct candidates, so tau >= 10th-best bf16 score; DELTA covers bf16<->fp32.
__global__ void tau_kernel(const float* __restrict__ minbuf, float* __restrict__ tau, int m) {
    __shared__ float sh[64 * 40];
    const int qi = threadIdx.x & 63, part = threadIdx.x >> 6;
    const int q = blockIdx.x * 64 + qi;
    float ms[KTOP];
#pragma unroll
    for (int e = 0; e < KTOP; ++e) ms[e] = INFINITY;
#pragma unroll 4
    for (int i = 0; i < 128; ++i) {
        float v = minbuf[(size_t)(part * 128 + i) * m + q];
        if (v < ms[9]) insert10s(v, ms);
    }
#pragma unroll
    for (int e = 0; e < KTOP; ++e) sh[qi * 40 + part * 10 + e] = ms[e];
    __syncthreads();
    if (threadIdx.x < 64) {
        const int qq = blockIdx.x * 64 + threadIdx.x;
        float fs[KTOP];
#pragma unroll
        for (int e = 0; e < KTOP; ++e) fs[e] = INFINITY;
        for (int x = 0; x < 40; ++x) {
            float v = sh[threadIdx.x * 40 + x];
            if (v < fs[9]) insert10s(v, fs);
        }
        tau[qq] = fs[9] + DELTA;
    }
}

// ---------- list build: per-seg qualifying queries + flat work queue ----------
// Seg s can emit for query q iff min of its 4 quarter-mins <= tau[q]; exact equivalence
// with pass-2's emission test (same acc values, *-2 / *0.5 are exact).
__global__ void list_build(const float* __restrict__ minbuf, const float* __restrict__ tau,
                           int* __restrict__ qlist, int* __restrict__ wq,
                           int* __restrict__ wq_n, int m) {
    __shared__ int lq[MQ];
    __shared__ int lcnt;
    const int s = blockIdx.x, tid = threadIdx.x;
    if (tid == 0) lcnt = 0;
    __syncthreads();
    const float* r0 = minbuf + (size_t)(4 * s) * m;
    const float* r1 = minbuf + (size_t)(4 * s + 1) * m;
    const float* r2 = minbuf + (size_t)(4 * s + 2) * m;
    const float* r3 = minbuf + (size_t)(4 * s + 3) * m;
    for (int q = tid; q < m; q += 256) {
        float v = fminf(fminf(r0[q], r1[q]), fminf(r2[q], r3[q]));
        if (v <= tau[q]) { int p = atomicAdd(&lcnt, 1); lq[p] = q; }
    }
    __syncthreads();
    const int c = lcnt;
    const int padded = (c + 255) & ~255;
    for (int i = c + tid; i < padded; i += 256) lq[i] = -1;   // sentinel queries
    __syncthreads();
    for (int i = tid; i < padded; i += 256) qlist[(size_t)s * MQ + i] = lq[i];
    if (tid == 0 && c > 0) {
        const int nqc = padded >> 8;
        int base = atomicAdd(wq_n, nqc * NPART);
        for (int qc = 0; qc < nqc; ++qc)
            for (int p = 0; p < NPART; ++p)
                wq[base++] = (s << 6) | (qc << 3) | p;
    }
}

// ---------- pass 2: sparse candidate emission over the work queue ----------
__global__ __launch_bounds__(256, 4) void nd_pass2(
        const ushort* __restrict__ Xbp, const ushort* __restrict__ Xtb,
        const uint* __restrict__ x2wp, const float* __restrict__ tau,
        int* __restrict__ cnt, int* __restrict__ buf,
        const int* __restrict__ qlist, const int* __restrict__ wq,
        const int* __restrict__ wq_n, int m) {
    __shared__ __align__(16) ushort As[2 * BUFU];

    const int t = threadIdx.x;
    const int l = t & 63, wv = t >> 6;
    const int half = l >> 5;
    const int u0 = t, u1 = 256 + t;
    const int L0 = swz16(u0) * 8, L1 = swz16(u1) * 8;
    const uint4* Xg = (const uint4*)Xbp;
    int raddr[8];
#pragma unroll
    for (int ks = 0; ks < 8; ++ks)
        raddr[ks] = ((l & 31) * 16 + ((2 * ks + half) ^ (l & 7))) * 8;
    const int T = wq_n[0];

    for (int w = blockIdx.x; w < T; w += gridDim.x) {
        const int it = wq[w];
        const int s = it >> 6, qc = (it >> 3) & 7, part = it & 7;
        const int t0 = s * NT + part * TPP;
        const int lbase = s * MQ + qc * 256 + wv * 64 + (l & 31);
        const int qi0 = qlist[lbase], qi1 = qlist[lbase + 32];
        const int q0e = qi0 < 0 ? 0 : qi0, q1e = qi1 < 0 ? 0 : qi1;

        short8 Bf[8][2];
#pragma unroll
        for (int sk = 0; sk < 8; ++sk) {
            Bf[sk][0] = *(const short8*)(Xtb + (size_t)q0e * D + sk * 16 + half * 8);
            Bf[sk][1] = *(const short8*)(Xtb + (size_t)q1e * D + sk * 16 + half * 8);
        }
        short8 B8 = (short8)(short)0;
        if (l < 32) { B8[0] = (short)0xBF00; B8[1] = (short)0xBF00; }
        const float tp0 = (qi0 < 0) ? INFINITY : (-0.5f * tau[qi0]);
        const float tp1 = (qi1 < 0) ? INFINITY : (-0.5f * tau[qi1]);

        uint4 r0 = Xg[(size_t)t0 * TUNITS + u0];
        uint4 r1 = Xg[(size_t)t0 * TUNITS + u1];
        uint pkc = x2wp[t0 * TILE_C + (l & 31)];

        for (int t2 = t0; t2 < t0 + TPP; ++t2) {
            ushort* Lb = &As[(t2 & 1) * BUFU];
            *(uint4*)&Lb[L0] = r0;
            *(uint4*)&Lb[L1] = r1;
            __syncthreads();

            const size_t gb = (size_t)(t2 + 1) * TUNITS;   // overrun covered by pad tiles
            r0 = Xg[gb + u0];
            r1 = Xg[gb + u1];
            uint pkn = x2wp[(t2 + 1) * TILE_C + (l & 31)];

            f32x16 acc0 = (f32x16)0.f, acc1 = (f32x16)0.f;
#pragma unroll
            for (int ks = 0; ks < 8; ++ks) {
                short8 a = *(const short8*)&Lb[raddr[ks]];
                acc0 = __builtin_amdgcn_mfma_f32_32x32x16_bf16(a, Bf[ks][0], acc0, 0, 0, 0);
                acc1 = __builtin_amdgcn_mfma_f32_32x32x16_bf16(a, Bf[ks][1], acc1, 0, 0, 0);
            }
            short8 av9 = (short8)(short)0;
            av9[0] = (short)(pkc & 0xffff);
            av9[1] = (short)(pkc >> 16);
            acc0 = __builtin_amdgcn_mfma_f32_32x32x16_bf16(av9, B8, acc0, 0, 0, 0);
            acc1 = __builtin_amdgcn_mfma_f32_32x32x16_bf16(av9, B8, acc1, 0, 0, 0);
            pkc = pkn;

            float h0 = -INFINITY, h1 = -INFINITY;
#pragma unroll
            for (int r = 0; r < 16; ++r) { h0 = fmaxf(h0, acc0[r]); h1 = fmaxf(h1, acc1[r]); }
            const int base = t2 * TILE_C;
            if (__any(h0 >= tp0)) {
#pragma unroll
                for (int r = 0; r < 16; ++r)
                    if (acc0[r] >= tp0) emit_cand(qi0, base + (r & 3) + 8 * (r >> 2) + 4 * half, cnt, buf);
            }
            if (__any(h1 >= tp1)) {
#pragma unroll
                for (int r = 0; r < 16; ++r)
                    if (acc1[r] >= tp1) emit_cand(qi1, base + (r & 3) + 8 * (r >> 2) + 4 * half, cnt, buf);
            }
        }
        __syncthreads();   // item boundary: next item's first LDS write vs this item's last reads
    }
}

// ---------- exact fp32 rescore ----------
__global__ void rescore_kernel(const float* __restrict__ Xtf, const float* __restrict__ Xf,
                               const float* __restrict__ w, const float* __restrict__ x2wf,
                               const float* __restrict__ q2f, const int* __restrict__ cnt,
                               const int* __restrict__ buf, float* __restrict__ out, int m) {
    __shared__ float sS[CAP], sW[CAP];
    const int q = blockIdx.x, l = threadIdx.x;
    const int c = min(cnt[q], CAP);
    const bool v0 = l < c, v1 = l + 64 < c;
    const int j0 = v0 ? buf[q * CAP + l] : 0;
    const int j1 = v1 ? buf[q * CAP + l + 64] : 0;
    const float4* Q4 = (const float4*)Xtf + (size_t)q * 32;
    const float4* A4 = (const float4*)Xf + (size_t)j0 * 32;
    const float4* B4 = (const float4*)Xf + (size_t)j1 * 32;
    float acc0 = 0.f, acc1 = 0.f;
#pragma unroll 8
    for (int d = 0; d < 32; ++d) {
        float4 qv = Q4[d];
        float4 a = A4[d], b = B4[d];
        acc0 = fmaf(qv.x, a.x, fmaf(qv.y, a.y, fmaf(qv.z, a.z, fmaf(qv.w, a.w, acc0))));
        acc1 = fmaf(qv.x, b.x, fmaf(qv.y, b.y, fmaf(qv.z, b.z, fmaf(qv.w, b.w, acc1))));
    }
    sS[l]      = v0 ? (x2wf[j0] - 2.f * acc0) : INFINITY;
    sW[l]      = v0 ? w[j0] : 0.f;
    sS[l + 64] = v1 ? (x2wf[j1] - 2.f * acc1) : INFINITY;
    sW[l + 64] = v1 ? w[j1] : 0.f;
    __syncthreads();
    if (l == 0) {
        float ls[KTOP], lw[KTOP];
#pragma unroll
        for (int e = 0; e < KTOP; ++e) { ls[e] = INFINITY; lw[e] = 0.f; }
        for (int i = 0; i < c; ++i)
            if (sS[i] < ls[9]) insert10(sS[i], sW[i], ls, lw);
        float q2v = q2f[q];
        float mxv = -INFINITY;
#pragma unroll
        for (int e = 0; e < KTOP; ++e) {
            if (ls[e] < 1e30f) {
                float d2 = fmaxf(q2v + ls[e] + lw[e], 0.f);
                mxv = fmaxf(mxv, lw[e] - sqrtf(d2));
            }
        }
        out[q] = mxv;
    }
}

// ---------- launch ----------
extern "C" void kernel_launch(void* const* d_in, const int* in_sizes, int n_in,
                              void* d_out, int out_size, void* d_ws, size_t ws_size,
                              hipStream_t stream) {
    const float* Xt = (const float*)d_in[0];
    const float* X  = (const float*)d_in[1];
    const float* w  = (const float*)d_in[2];
    const int m = in_sizes[0] / D;   // 2048
    const int n = in_sizes[1] / D;   // 100000

    auto align256 = [](size_t x) { return (x + 255) & ~(size_t)255; };
    char* p = (char*)d_ws;
    ushort* Xbp  = (ushort*)p;  p += align256((size_t)NPAD * ROWU * 2);     // ~26.2 MB
    ushort* Xtb  = (ushort*)p;  p += align256((size_t)m * D * 2);
    uint*   x2wp = (uint*)p;    p += align256((size_t)NPAD * 4);
    float*  x2wf = (float*)p;   p += align256((size_t)n * 4);
    float*  q2f  = (float*)p;   p += align256((size_t)m * 4);
    float*  minb = (float*)p;   p += align256((size_t)4 * NSEG * m * 4);    // 4 MB
    float*  tau  = (float*)p;   p += align256((size_t)m * 4);
    int*    cnt  = (int*)p;     p += align256((size_t)m * 4);
    int*    buf  = (int*)p;     p += align256((size_t)m * CAP * 4);
    int*    qlist= (int*)p;     p += align256((size_t)NSEG * MQ * 4);       // 1 MB
    int*    wq   = (int*)p;     p += align256((size_t)WQCAP * 4);
    int*    wq_n = (int*)p;     p += align256((size_t)256);

    const int nblocksA = (NPAD + 3) / 4;
    const int nblocksB = (m + 3) / 4;
    prep_kernel<<<nblocksA + nblocksB, 256, 0, stream>>>(Xt, X, w, Xbp, Xtb, x2wp, x2wf, q2f,
                                                         cnt, wq_n, n, m, nblocksA);

    dim3 grid1(NHSEG, m / 256);
    nd_pass1<<<grid1, 256, 0, stream>>>(Xbp, Xtb, x2wp, minb, m);
    tau_kernel<<<m / 64, 256, 0, stream>>>(minb, tau, m);
    list_build<<<NSEG, 256, 0, stream>>>(minb, tau, qlist, wq, wq_n, m);
    nd_pass2<<<1024, 256, 0, stream>>>(Xbp, Xtb, x2wp, tau, cnt, buf, qlist, wq, wq_n, m);
    rescore_kernel<<<m, 64, 0, stream>>>(Xt, X, w, x2wf, q2f, cnt, buf, (float*)d_out, m);
}

// Round 10
// 251.700 us; speedup vs baseline: 1.3658x; 1.2673x over previous
//
#include <hip/hip_runtime.h>
#include <math.h>

typedef __attribute__((ext_vector_type(8))) short short8;
typedef __attribute__((ext_vector_type(16))) float f32x16;

#define D      128
#define NSEG   128
#define SEGC   800           // candidates per segment (multiple of 32)
#define NT     25            // SEGC / 32
#define TPP    5             // tiles per pass-2 work item (NT/NPART)
#define NPART  5
#define TILE_C 32
#define KTOP   10
#define CAP    128
#define DELTA  3.0f
#define NPAD   (NSEG * SEGC + TILE_C)   // +32 rows for last-tile prefetch overrun (== 102432)
#define ROWU   144           // ushorts per padded row (288 B): 128 data + x2w hi/lo + zeros
#define TUNITS (TILE_C * 18) // 576 16B-units per tile
#define BUFU   (TUNITS * 8)  // 4608 ushorts per LDS buffer
#define MQ     2048          // m (fixed by problem) — LDS list size in list_build
#define WQCAP  (NSEG * 8 * NPART)

// LDS swizzle: unit (r,kb) stored at r*18 + (kb ^ ((r>>2)&1)).  Flipping kb-bit0 by row-bit2
// makes each consecutive-8-lane b128 phase hit 8 distinct bank-quads (conflict-free).
__device__ __forceinline__ int lds_unit(int u) {
    int r = u / 18, kb = u % 18;
    return r * 18 + (kb ^ ((r >> 2) & 1));
}

// ---------- helpers ----------
__device__ __forceinline__ ushort f2bf(float f) {
    uint u = __float_as_uint(f);
    uint r = (u + 0x7FFFu + ((u >> 16) & 1u)) >> 16;
    return (ushort)r;
}

__device__ __forceinline__ uint packx2(float x2w) {
    ushort h = f2bf(x2w);
    float hf = __uint_as_float(((uint)h) << 16);
    ushort lo = f2bf(x2w - hf);
    return (uint)h | ((uint)lo << 16);
}

__device__ __forceinline__ void insert10(float s, float v, float ls[KTOP], float lw[KTOP]) {
    ls[9] = s; lw[9] = v;
#pragma unroll
    for (int p = 9; p > 0; --p) {
        bool sw = ls[p] < ls[p - 1];
        float ts = sw ? ls[p - 1] : ls[p];
        float tl = sw ? ls[p]     : ls[p - 1];
        float tv = sw ? lw[p - 1] : lw[p];
        float tu = sw ? lw[p]     : lw[p - 1];
        ls[p] = ts; ls[p - 1] = tl;
        lw[p] = tv; lw[p - 1] = tu;
    }
}

__device__ __forceinline__ void insert10s(float s, float ms[KTOP]) {
    ms[9] = s;
#pragma unroll
    for (int p = 9; p > 0; --p) {
        float a = fminf(ms[p - 1], ms[p]);
        float b = fmaxf(ms[p - 1], ms[p]);
        ms[p - 1] = a; ms[p] = b;
    }
}

// ---------- fused prep: candidates (padded 288B rows, bf16 + x2w hi/lo), queries, cnt zero ----------
__global__ void prep_kernel(const float* __restrict__ Xt, const float* __restrict__ X,
                            const float* __restrict__ w,
                            ushort* __restrict__ Xbp, ushort* __restrict__ Xtb,
                            float* __restrict__ x2wf, float* __restrict__ q2f,
                            int* __restrict__ cnt, int* __restrict__ wq_n,
                            int n, int m, int nblocksA) {
    if (blockIdx.x == 0 && threadIdx.x == 0) wq_n[0] = 0;
    int wave = threadIdx.x >> 6, lane = threadIdx.x & 63;
    if ((int)blockIdx.x < nblocksA) {
        int row = blockIdx.x * 4 + wave;
        if (row >= NPAD) return;
        ushort* rowp = Xbp + (size_t)row * ROWU;
        if (row < n) {
            float2 v = ((const float2*)X)[(size_t)row * 64 + lane];
            ((ushort2*)rowp)[lane] = make_ushort2(f2bf(v.x), f2bf(v.y));
            float s = v.x * v.x + v.y * v.y;
#pragma unroll
            for (int o = 32; o; o >>= 1) s += __shfl_xor(s, o, 64);
            float x2w = s - w[row];
            if (lane == 0) x2wf[row] = x2w;
            if (lane < 8) ((uint*)rowp)[64 + lane] = (lane == 0) ? packx2(x2w) : 0u;
        } else {
            ((ushort2*)rowp)[lane] = make_ushort2(0, 0);      // sentinel: zero data
            if (lane < 8) ((uint*)rowp)[64 + lane] = (lane == 0) ? packx2(1e30f) : 0u;
        }
    } else {
        int qb = blockIdx.x - nblocksA;
        int row = qb * 4 + wave;
        int tid = qb * 256 + threadIdx.x;
        if (tid < m) cnt[tid] = 0;
        if (row >= m) return;
        float2 v = ((const float2*)Xt)[(size_t)row * 64 + lane];
        ((ushort2*)Xtb)[(size_t)row * 64 + lane] = make_ushort2(f2bf(v.x), f2bf(v.y));
        float s = v.x * v.x + v.y * v.y;
#pragma unroll
        for (int o = 32; o; o >>= 1) s += __shfl_xor(s, o, 64);
        if (lane == 0) q2f[row] = s;
    }
}

__device__ __forceinline__ void emit_cand(int q, int c, int* cnt, int* buf) {
    int pos = atomicAdd(&cnt[q], 1);
    if (pos < CAP) buf[q * CAP + pos] = c;
}

// ---------- pass 1: full GEMM, per-(query, half-seg) stream mins ----------
// 1024 blocks = 128 segs x 8 query-blocks = 4 blocks/CU (4 waves/SIMD). Block: 4 waves x
// 64 queries each. Wave tile: 32 cands x 64 queries per k-step (2 MFMAs x 9 ksteps).
// A staging: global->VGPR + ds_write_b128 double-buffer, ONE __syncthreads per tile
// (2-buffer rotation => barrier chain orders iter t+2's write-A after iter t's reads-A).
// acc = q.x - 0.5*x2w  =>  s = -2*acc.
__global__ __launch_bounds__(256, 4) void nd_pass1(
        const ushort* __restrict__ Xbp, const ushort* __restrict__ Xtb,
        float* __restrict__ minbuf, int m) {
    __shared__ __align__(16) ushort As[2 * BUFU];   // 2 x 9216 B

    const int t = threadIdx.x;
    const int l = t & 63, wv = t >> 6;
    const int half = l >> 5;
    const int seg = blockIdx.x;
    const int qbase = blockIdx.y * 256 + wv * 64;
    const int q0 = qbase + (l & 31);                 // query for qsub 0 (qsub 1 -> +32)
    const int tile0 = seg * NT;
    const int halfx = half ^ ((l >> 2) & 1);

    short8 Bf[8][2];
#pragma unroll
    for (int s = 0; s < 8; ++s)
#pragma unroll
        for (int qs = 0; qs < 2; ++qs)
            Bf[s][qs] = *(const short8*)(Xtb + (size_t)(q0 + qs * 32) * D + s * 16 + half * 8);
    short8 B8 = (short8)(short)0;
    if (l < 32) { B8[0] = (short)0xBF00; B8[1] = (short)0xBF00; }  // -0.5 at k=128,129

    float mx0 = -INFINITY, mx1 = -INFINITY;

    const int u0 = t, u1 = 256 + t, u2 = 512 + (t & 63);
    const int L0 = lds_unit(u0) * 8, L1 = lds_unit(u1) * 8, L2 = lds_unit(u2) * 8;
    const uint4* Xg = (const uint4*)Xbp;

    uint4 r0 = Xg[(size_t)tile0 * TUNITS + u0];
    uint4 r1 = Xg[(size_t)tile0 * TUNITS + u1];
    uint4 r2 = make_uint4(0, 0, 0, 0);
    if (t < 64) r2 = Xg[(size_t)tile0 * TUNITS + u2];

    for (int t2 = 0; t2 < NT; ++t2) {
        ushort* Lb = &As[(t2 & 1) * BUFU];
        *(uint4*)&Lb[L0] = r0;
        *(uint4*)&Lb[L1] = r1;
        if (t < 64) *(uint4*)&Lb[L2] = r2;
        __syncthreads();

        const size_t gb = (size_t)(tile0 + t2 + 1) * TUNITS;
        r0 = Xg[gb + u0];
        r1 = Xg[gb + u1];
        if (t < 64) r2 = Xg[gb + u2];

        f32x16 acc0 = (f32x16)0.f, acc1 = (f32x16)0.f;
#pragma unroll
        for (int ks = 0; ks < 9; ++ks) {
            const int kb = (ks < 8) ? (ks * 2 + halfx) : (16 + halfx);   // swizzled unit
            short8 a = *(const short8*)&Lb[((l & 31) * 18 + kb) * 8];
            short8 b0 = (ks < 8) ? Bf[ks][0] : B8;
            short8 b1 = (ks < 8) ? Bf[ks][1] : B8;
            acc0 = __builtin_amdgcn_mfma_f32_32x32x16_bf16(a, b0, acc0, 0, 0, 0);
            acc1 = __builtin_amdgcn_mfma_f32_32x32x16_bf16(a, b1, acc1, 0, 0, 0);
        }

        float h0 = -INFINITY, h1 = -INFINITY;
#pragma unroll
        for (int r = 0; r < 16; ++r) { h0 = fmaxf(h0, acc0[r]); h1 = fmaxf(h1, acc1[r]); }
        mx0 = fmaxf(mx0, h0);
        mx1 = fmaxf(mx1, h1);
    }

    size_t rowi = (size_t)(seg * 2 + half) * m;
    minbuf[rowi + q0]      = -2.f * mx0;
    minbuf[rowi + q0 + 32] = -2.f * mx1;
}

// ---------- tau: 10th smallest of 2*NSEG stream-mins per query, + margin ----------
__global__ void tau_kernel(const float* __restrict__ minbuf, float* __restrict__ tau, int m) {
    __shared__ float sh[64 * 40];
    const int qi = threadIdx.x & 63, part = threadIdx.x >> 6;
    const int q = blockIdx.x * 64 + qi;
    float ms[KTOP];
#pragma unroll
    for (int e = 0; e < KTOP; ++e) ms[e] = INFINITY;
#pragma unroll 4
    for (int i = 0; i < 64; ++i) {
        float v = minbuf[(size_t)(part * 64 + i) * m + q];
        if (v < ms[9]) insert10s(v, ms);
    }
#pragma unroll
    for (int e = 0; e < KTOP; ++e) sh[qi * 40 + part * 10 + e] = ms[e];
    __syncthreads();
    if (threadIdx.x < 64) {
        const int qq = blockIdx.x * 64 + threadIdx.x;
        float fs[KTOP];
#pragma unroll
        for (int e = 0; e < KTOP; ++e) fs[e] = INFINITY;
        for (int x = 0; x < 40; ++x) {
            float v = sh[threadIdx.x * 40 + x];
            if (v < fs[9]) insert10s(v, fs);
        }
        tau[qq] = fs[9] + DELTA;
    }
}

// ---------- list build: per-seg qualifying queries + flat work queue ----------
// Seg s can emit for query q iff min(minbuf[2s][q], minbuf[2s+1][q]) <= tau[q]; exact
// equivalence with pass-2's emission test (same acc values, *-2 / *0.5 are exact).
// Work item = (seg, 256-query chunk, 5-tile part); expect ~10-20 segs/query ->
// ~128 chunks -> ~640 items (tile-split keeps >2 blocks/CU of parallelism).
__global__ void list_build(const float* __restrict__ minbuf, const float* __restrict__ tau,
                           int* __restrict__ qlist, int* __restrict__ wq,
                           int* __restrict__ wq_n, int m) {
    __shared__ int lq[MQ];
    __shared__ int lcnt;
    const int s = blockIdx.x, tid = threadIdx.x;
    if (tid == 0) lcnt = 0;
    __syncthreads();
    const float* r0 = minbuf + (size_t)(2 * s) * m;
    const float* r1 = minbuf + (size_t)(2 * s + 1) * m;
    for (int q = tid; q < m; q += 256) {
        float v = fminf(r0[q], r1[q]);
        if (v <= tau[q]) { int p = atomicAdd(&lcnt, 1); lq[p] = q; }
    }
    __syncthreads();
    const int c = lcnt;
    const int padded = (c + 255) & ~255;
    for (int i = c + tid; i < padded; i += 256) lq[i] = -1;   // sentinel queries
    __syncthreads();
    for (int i = tid; i < padded; i += 256) qlist[(size_t)s * MQ + i] = lq[i];
    if (tid == 0 && c > 0) {
        const int nqc = padded >> 8;
        int base = atomicAdd(wq_n, nqc * NPART);
        for (int qc = 0; qc < nqc; ++qc)
            for (int p = 0; p < NPART; ++p)
                wq[base++] = (s << 6) | (qc << 3) | p;
    }
}

// ---------- pass 2: sparse candidate emission over the work queue ----------
__global__ __launch_bounds__(256, 4) void nd_pass2(
        const ushort* __restrict__ Xbp, const ushort* __restrict__ Xtb,
        const float* __restrict__ tau,
        int* __restrict__ cnt, int* __restrict__ buf,
        const int* __restrict__ qlist, const int* __restrict__ wq,
        const int* __restrict__ wq_n, int m) {
    __shared__ __align__(16) ushort As[2 * BUFU];

    const int t = threadIdx.x;
    const int l = t & 63, wv = t >> 6;
    const int half = l >> 5;
    const int halfx = half ^ ((l >> 2) & 1);
    const int u0 = t, u1 = 256 + t, u2 = 512 + (t & 63);
    const int L0 = lds_unit(u0) * 8, L1 = lds_unit(u1) * 8, L2 = lds_unit(u2) * 8;
    const uint4* Xg = (const uint4*)Xbp;
    const int T = wq_n[0];

    for (int w = blockIdx.x; w < T; w += gridDim.x) {
        const int it = wq[w];
        const int s = it >> 6, qc = (it >> 3) & 7, part = it & 7;
        const int t0 = s * NT + part * TPP;
        const int lbase = s * MQ + qc * 256 + wv * 64 + (l & 31);
        const int qi0 = qlist[lbase], qi1 = qlist[lbase + 32];
        const int q0e = qi0 < 0 ? 0 : qi0, q1e = qi1 < 0 ? 0 : qi1;

        short8 Bf[8][2];
#pragma unroll
        for (int sk = 0; sk < 8; ++sk) {
            Bf[sk][0] = *(const short8*)(Xtb + (size_t)q0e * D + sk * 16 + half * 8);
            Bf[sk][1] = *(const short8*)(Xtb + (size_t)q1e * D + sk * 16 + half * 8);
        }
        short8 B8 = (short8)(short)0;
        if (l < 32) { B8[0] = (short)0xBF00; B8[1] = (short)0xBF00; }
        const float tp0 = (qi0 < 0) ? INFINITY : (-0.5f * tau[qi0]);
        const float tp1 = (qi1 < 0) ? INFINITY : (-0.5f * tau[qi1]);

        uint4 r0 = Xg[(size_t)t0 * TUNITS + u0];
        uint4 r1 = Xg[(size_t)t0 * TUNITS + u1];
        uint4 r2 = make_uint4(0, 0, 0, 0);
        if (t < 64) r2 = Xg[(size_t)t0 * TUNITS + u2];

        for (int t2 = t0; t2 < t0 + TPP; ++t2) {
            ushort* Lb = &As[(t2 & 1) * BUFU];
            *(uint4*)&Lb[L0] = r0;
            *(uint4*)&Lb[L1] = r1;
            if (t < 64) *(uint4*)&Lb[L2] = r2;
            __syncthreads();

            const size_t gb = (size_t)(t2 + 1) * TUNITS;   // overrun covered by pad tiles
            r0 = Xg[gb + u0];
            r1 = Xg[gb + u1];
            if (t < 64) r2 = Xg[gb + u2];

            f32x16 acc0 = (f32x16)0.f, acc1 = (f32x16)0.f;
#pragma unroll
            for (int ks = 0; ks < 9; ++ks) {
                const int kb = (ks < 8) ? (ks * 2 + halfx) : (16 + halfx);
                short8 a = *(const short8*)&Lb[((l & 31) * 18 + kb) * 8];
                short8 b0 = (ks < 8) ? Bf[ks][0] : B8;
                short8 b1 = (ks < 8) ? Bf[ks][1] : B8;
                acc0 = __builtin_amdgcn_mfma_f32_32x32x16_bf16(a, b0, acc0, 0, 0, 0);
                acc1 = __builtin_amdgcn_mfma_f32_32x32x16_bf16(a, b1, acc1, 0, 0, 0);
            }

            float h0 = -INFINITY, h1 = -INFINITY;
#pragma unroll
            for (int r = 0; r < 16; ++r) { h0 = fmaxf(h0, acc0[r]); h1 = fmaxf(h1, acc1[r]); }
            const int base = t2 * TILE_C;
            if (__any(h0 >= tp0)) {
#pragma unroll
                for (int r = 0; r < 16; ++r)
                    if (acc0[r] >= tp0) emit_cand(qi0, base + (r & 3) + 8 * (r >> 2) + 4 * half, cnt, buf);
            }
            if (__any(h1 >= tp1)) {
#pragma unroll
                for (int r = 0; r < 16; ++r)
                    if (acc1[r] >= tp1) emit_cand(qi1, base + (r & 3) + 8 * (r >> 2) + 4 * half, cnt, buf);
            }
        }
        __syncthreads();   // item boundary: next item's first LDS write vs this item's last reads
    }
}

// ---------- exact fp32 rescore ----------
__global__ void rescore_kernel(const float* __restrict__ Xtf, const float* __restrict__ Xf,
                               const float* __restrict__ w, const float* __restrict__ x2wf,
                               const float* __restrict__ q2f, const int* __restrict__ cnt,
                               const int* __restrict__ buf, float* __restrict__ out, int m) {
    __shared__ float sS[CAP], sW[CAP];
    const int q = blockIdx.x, l = threadIdx.x;
    const int c = min(cnt[q], CAP);
    const bool v0 = l < c, v1 = l + 64 < c;
    const int j0 = v0 ? buf[q * CAP + l] : 0;
    const int j1 = v1 ? buf[q * CAP + l + 64] : 0;
    const float4* Q4 = (const float4*)Xtf + (size_t)q * 32;
    const float4* A4 = (const float4*)Xf + (size_t)j0 * 32;
    const float4* B4 = (const float4*)Xf + (size_t)j1 * 32;
    float acc0 = 0.f, acc1 = 0.f;
#pragma unroll 8
    for (int d = 0; d < 32; ++d) {
        float4 qv = Q4[d];
        float4 a = A4[d], b = B4[d];
        acc0 = fmaf(qv.x, a.x, fmaf(qv.y, a.y, fmaf(qv.z, a.z, fmaf(qv.w, a.w, acc0))));
        acc1 = fmaf(qv.x, b.x, fmaf(qv.y, b.y, fmaf(qv.z, b.z, fmaf(qv.w, b.w, acc1))));
    }
    sS[l]      = v0 ? (x2wf[j0] - 2.f * acc0) : INFINITY;
    sW[l]      = v0 ? w[j0] : 0.f;
    sS[l + 64] = v1 ? (x2wf[j1] - 2.f * acc1) : INFINITY;
    sW[l + 64] = v1 ? w[j1] : 0.f;
    __syncthreads();
    if (l == 0) {
        float ls[KTOP], lw[KTOP];
#pragma unroll
        for (int e = 0; e < KTOP; ++e) { ls[e] = INFINITY; lw[e] = 0.f; }
        for (int i = 0; i < c; ++i)
            if (sS[i] < ls[9]) insert10(sS[i], sW[i], ls, lw);
        float q2v = q2f[q];
        float mxv = -INFINITY;
#pragma unroll
        for (int e = 0; e < KTOP; ++e) {
            if (ls[e] < 1e30f) {
                float d2 = fmaxf(q2v + ls[e] + lw[e], 0.f);
                mxv = fmaxf(mxv, lw[e] - sqrtf(d2));
            }
        }
        out[q] = mxv;
    }
}

// ---------- launch ----------
extern "C" void kernel_launch(void* const* d_in, const int* in_sizes, int n_in,
                              void* d_out, int out_size, void* d_ws, size_t ws_size,
                              hipStream_t stream) {
    const float* Xt = (const float*)d_in[0];
    const float* X  = (const float*)d_in[1];
    const float* w  = (const float*)d_in[2];
    const int m = in_sizes[0] / D;   // 2048
    const int n = in_sizes[1] / D;   // 100000

    auto align256 = [](size_t x) { return (x + 255) & ~(size_t)255; };
    char* p = (char*)d_ws;
    ushort* Xbp  = (ushort*)p;  p += align256((size_t)NPAD * ROWU * 2);     // ~29.5 MB
    ushort* Xtb  = (ushort*)p;  p += align256((size_t)m * D * 2);
    float*  x2wf = (float*)p;   p += align256((size_t)n * 4);
    float*  q2f  = (float*)p;   p += align256((size_t)m * 4);
    float*  minb = (float*)p;   p += align256((size_t)2 * NSEG * m * 4);    // 2 MB
    float*  tau  = (float*)p;   p += align256((size_t)m * 4);
    int*    cnt  = (int*)p;     p += align256((size_t)m * 4);
    int*    buf  = (int*)p;     p += align256((size_t)m * CAP * 4);
    int*    qlist= (int*)p;     p += align256((size_t)NSEG * MQ * 4);       // 1 MB
    int*    wq   = (int*)p;     p += align256((size_t)WQCAP * 4);
    int*    wq_n = (int*)p;     p += align256((size_t)256);

    const int nblocksA = (NPAD + 3) / 4;
    const int nblocksB = (m + 3) / 4;
    prep_kernel<<<nblocksA + nblocksB, 256, 0, stream>>>(Xt, X, w, Xbp, Xtb, x2wf, q2f,
                                                         cnt, wq_n, n, m, nblocksA);

    dim3 grid1(NSEG, m / 256);
    nd_pass1<<<grid1, 256, 0, stream>>>(Xbp, Xtb, minb, m);
    tau_kernel<<<m / 64, 256, 0, stream>>>(minb, tau, m);
    list_build<<<NSEG, 256, 0, stream>>>(minb, tau, qlist, wq, wq_n, m);
    nd_pass2<<<1024, 256, 0, stream>>>(Xbp, Xtb, tau, cnt, buf, qlist, wq, wq_n, m);
    rescore_kernel<<<m, 64, 0, stream>>>(Xt, X, w, x2wf, q2f, cnt, buf, (float*)d_out, m);
}

// Round 11
// 244.890 us; speedup vs baseline: 1.4038x; 1.0278x over previous
//
#include <hip/hip_runtime.h>
#include <math.h>

typedef __attribute__((ext_vector_type(8))) short short8;
typedef __attribute__((ext_vector_type(16))) float f32x16;

#define D      128
#define NSEG   128
#define SEGC   800           // candidates per segment (multiple of 32)
#define NT     25            // SEGC / 32
#define TPP    5             // tiles per pass-2 work item (NT/NPART)
#define NPART  5
#define TILE_C 32
#define KTOP   10
#define CAP    128
#define DELTA  3.0f
#define NPAD   (NSEG * SEGC + 3 * TILE_C)  // +3 pad tiles for 3-deep prefetch overrun (== 102496)
#define ROWU   144           // ushorts per padded row (288 B): 128 data + x2w hi/lo + zeros
#define TUNITS (TILE_C * 18) // 576 16B-units per tile
#define TBYTES (TUNITS * 16) // 9216 B per tile
#define BUFU   (TUNITS * 8)  // 4608 ushorts per LDS buffer
#define MQ     2048          // m (fixed by problem) — LDS list size in list_build
#define WQCAP  (NSEG * 8 * NPART)

// LDS swizzle: unit (r,kb) stored at r*18 + (kb ^ ((r>>2)&1)); involution.
// pass1 stages via global_load_lds (linear LDS dest): pre-swizzle the per-lane global
// source so LDS[s] = global[swz(s)]  =>  LDS[swz(u)] = global[u] — identical layout to
// the ds_write path; compute read addressing unchanged.
__device__ __forceinline__ int lds_unit(int u) {
    int r = u / 18, kb = u % 18;
    return r * 18 + (kb ^ ((r >> 2) & 1));
}

__device__ __forceinline__ void gl_lds16(const void* g, void* lds) {
    __builtin_amdgcn_global_load_lds(
        (const __attribute__((address_space(1))) unsigned int*)g,
        (__attribute__((address_space(3))) unsigned int*)lds, 16, 0, 0);
}
__device__ __forceinline__ void gl_lds4(const void* g, void* lds) {
    __builtin_amdgcn_global_load_lds(
        (const __attribute__((address_space(1))) unsigned int*)g,
        (__attribute__((address_space(3))) unsigned int*)lds, 4, 0, 0);
}

// ---------- helpers ----------
__device__ __forceinline__ ushort f2bf(float f) {
    uint u = __float_as_uint(f);
    uint r = (u + 0x7FFFu + ((u >> 16) & 1u)) >> 16;
    return (ushort)r;
}

__device__ __forceinline__ uint packx2(float x2w) {
    ushort h = f2bf(x2w);
    float hf = __uint_as_float(((uint)h) << 16);
    ushort lo = f2bf(x2w - hf);
    return (uint)h | ((uint)lo << 16);
}

__device__ __forceinline__ void insert10(float s, float v, float ls[KTOP], float lw[KTOP]) {
    ls[9] = s; lw[9] = v;
#pragma unroll
    for (int p = 9; p > 0; --p) {
        bool sw = ls[p] < ls[p - 1];
        float ts = sw ? ls[p - 1] : ls[p];
        float tl = sw ? ls[p]     : ls[p - 1];
        float tv = sw ? lw[p - 1] : lw[p];
        float tu = sw ? lw[p]     : lw[p - 1];
        ls[p] = ts; ls[p - 1] = tl;
        lw[p] = tv; lw[p - 1] = tu;
    }
}

__device__ __forceinline__ void insert10s(float s, float ms[KTOP]) {
    ms[9] = s;
#pragma unroll
    for (int p = 9; p > 0; --p) {
        float a = fminf(ms[p - 1], ms[p]);
        float b = fmaxf(ms[p - 1], ms[p]);
        ms[p - 1] = a; ms[p] = b;
    }
}

// ---------- fused prep: candidates (padded 288B rows, bf16 + x2w hi/lo), queries, cnt zero ----------
__global__ void prep_kernel(const float* __restrict__ Xt, const float* __restrict__ X,
                            const float* __restrict__ w,
                            ushort* __restrict__ Xbp, ushort* __restrict__ Xtb,
                            float* __restrict__ x2wf, float* __restrict__ q2f,
                            int* __restrict__ cnt, int* __restrict__ wq_n,
                            int n, int m, int nblocksA) {
    if (blockIdx.x == 0 && threadIdx.x == 0) wq_n[0] = 0;
    int wave = threadIdx.x >> 6, lane = threadIdx.x & 63;
    if ((int)blockIdx.x < nblocksA) {
        int row = blockIdx.x * 4 + wave;
        if (row >= NPAD) return;
        ushort* rowp = Xbp + (size_t)row * ROWU;
        if (row < n) {
            float2 v = ((const float2*)X)[(size_t)row * 64 + lane];
            ((ushort2*)rowp)[lane] = make_ushort2(f2bf(v.x), f2bf(v.y));
            float s = v.x * v.x + v.y * v.y;
#pragma unroll
            for (int o = 32; o; o >>= 1) s += __shfl_xor(s, o, 64);
            float x2w = s - w[row];
            if (lane == 0) x2wf[row] = x2w;
            if (lane < 8) ((uint*)rowp)[64 + lane] = (lane == 0) ? packx2(x2w) : 0u;
        } else {
            ((ushort2*)rowp)[lane] = make_ushort2(0, 0);      // sentinel: zero data
            if (lane < 8) ((uint*)rowp)[64 + lane] = (lane == 0) ? packx2(1e30f) : 0u;
        }
    } else {
        int qb = blockIdx.x - nblocksA;
        int row = qb * 4 + wave;
        int tid = qb * 256 + threadIdx.x;
        if (tid < m) cnt[tid] = 0;
        if (row >= m) return;
        float2 v = ((const float2*)Xt)[(size_t)row * 64 + lane];
        ((ushort2*)Xtb)[(size_t)row * 64 + lane] = make_ushort2(f2bf(v.x), f2bf(v.y));
        float s = v.x * v.x + v.y * v.y;
#pragma unroll
        for (int o = 32; o; o >>= 1) s += __shfl_xor(s, o, 64);
        if (lane == 0) q2f[row] = s;
    }
}

__device__ __forceinline__ void emit_cand(int q, int c, int* cnt, int* buf) {
    int pos = atomicAdd(&cnt[q], 1);
    if (pos < CAP) buf[q * CAP + pos] = c;
}

// ---------- pass 1: full GEMM, per-(query, half-seg) stream mins ----------
// 1024 blocks = 128 segs x 8 query-blocks = 4 blocks/CU. Block: 4 waves x 64 queries.
// Wave tile: 32 cands x 64 queries per k-step (2 MFMAs x 9 ksteps).
// PIPELINE (T3/T4): staging via global_load_lds (NO staging VGPRs), 4 LDS buffers
// (36 KB/block), 3-tile-deep prefetch, ONE raw s_barrier per tile with COUNTED
// s_waitcnt vmcnt(6) — never vmcnt(0) in the loop. Per wave per tile: 2x gl_lds16 +
// 1x gl_lds4 = 3 vmem ops (uniform), so outstanding at loop top = 9 and vmcnt(6)
// means "this tile's 3 landed". Barrier then makes all waves' loads visible.
// Hazard: buffer (t+3)&3 was read at iter t-1; reads are in regs (lgkmcnt-consumed by
// MFMAs) before any wave reaches barrier t; stage issues after it.
// acc = q.x - 0.5*x2w  =>  s = -2*acc.
__global__ __launch_bounds__(256, 4) void nd_pass1(
        const ushort* __restrict__ Xbp, const ushort* __restrict__ Xtb,
        float* __restrict__ minbuf, int m) {
    __shared__ __align__(16) ushort As[4 * BUFU];   // 4 x 9216 B

    const int t = threadIdx.x;
    const int l = t & 63, wv = t >> 6;
    const int half = l >> 5;
    const int seg = blockIdx.x;
    const int qbase = blockIdx.y * 256 + wv * 64;
    const int q0 = qbase + (l & 31);                 // query for qsub 0 (qsub 1 -> +32)
    const int tile0 = seg * NT;
    const int halfx = half ^ ((l >> 2) & 1);

    short8 Bf[8][2];
#pragma unroll
    for (int s = 0; s < 8; ++s)
#pragma unroll
        for (int qs = 0; qs < 2; ++qs)
            Bf[s][qs] = *(const short8*)(Xtb + (size_t)(q0 + qs * 32) * D + s * 16 + half * 8);
    short8 B8 = (short8)(short)0;
    if (l < 32) { B8[0] = (short)0xBF00; B8[1] = (short)0xBF00; }  // -0.5 at k=128,129

    float mx0 = -INFINITY, mx1 = -INFINITY;

    // pre-swizzled per-lane global source byte offsets (within a tile) + wave dest base
    const int off0 = lds_unit(wv * 144 + l) * 16;
    const int off1 = lds_unit(wv * 144 + 64 + l) * 16;
    const int off2 = lds_unit(wv * 144 + 128 + (l >> 2)) * 16 + (l & 3) * 4;
    const int db = wv * 2304;                        // 144 units * 16 B per wave share
    const char* Xc = (const char*)Xbp;
    char* Ac = (char*)As;

    auto stage = [&](int T, int b) {
        const char* s = Xc + (size_t)T * TBYTES;
        char* d = Ac + b * TBYTES + db;
        gl_lds16(s + off0, d);
        gl_lds16(s + off1, d + 1024);
        gl_lds4 (s + off2, d + 2048);
    };

    // prologue: 3 tiles in flight (9 vmem ops outstanding per wave)
    stage(tile0 + 0, 0);
    stage(tile0 + 1, 1);
    stage(tile0 + 2, 2);

    for (int t2 = 0; t2 < NT; ++t2) {
        asm volatile("s_waitcnt vmcnt(6)" ::: "memory");   // tile t2's 3 loads landed
        __builtin_amdgcn_sched_barrier(0);
        __builtin_amdgcn_s_barrier();                      // all waves' tile-t2 loads visible
        stage(tile0 + t2 + 3, (t2 + 3) & 3);               // pads cover final overrun

        const ushort* Lb = &As[(t2 & 3) * BUFU];
        f32x16 acc0 = (f32x16)0.f, acc1 = (f32x16)0.f;
#pragma unroll
        for (int ks = 0; ks < 9; ++ks) {
            const int kb = (ks < 8) ? (ks * 2 + halfx) : (16 + halfx);   // swizzled unit
            short8 a = *(const short8*)&Lb[((l & 31) * 18 + kb) * 8];
            short8 b0 = (ks < 8) ? Bf[ks][0] : B8;
            short8 b1 = (ks < 8) ? Bf[ks][1] : B8;
            acc0 = __builtin_amdgcn_mfma_f32_32x32x16_bf16(a, b0, acc0, 0, 0, 0);
            acc1 = __builtin_amdgcn_mfma_f32_32x32x16_bf16(a, b1, acc1, 0, 0, 0);
        }

        float h0 = -INFINITY, h1 = -INFINITY;
#pragma unroll
        for (int r = 0; r < 16; ++r) { h0 = fmaxf(h0, acc0[r]); h1 = fmaxf(h1, acc1[r]); }
        mx0 = fmaxf(mx0, h0);
        mx1 = fmaxf(mx1, h1);
    }

    size_t rowi = (size_t)(seg * 2 + half) * m;
    minbuf[rowi + q0]      = -2.f * mx0;
    minbuf[rowi + q0 + 32] = -2.f * mx1;
}

// ---------- tau: 10th smallest of 2*NSEG stream-mins per query, + margin ----------
__global__ void tau_kernel(const float* __restrict__ minbuf, float* __restrict__ tau, int m) {
    __shared__ float sh[64 * 40];
    const int qi = threadIdx.x & 63, part = threadIdx.x >> 6;
    const int q = blockIdx.x * 64 + qi;
    float ms[KTOP];
#pragma unroll
    for (int e = 0; e < KTOP; ++e) ms[e] = INFINITY;
#pragma unroll 4
    for (int i = 0; i < 64; ++i) {
        float v = minbuf[(size_t)(part * 64 + i) * m + q];
        if (v < ms[9]) insert10s(v, ms);
    }
#pragma unroll
    for (int e = 0; e < KTOP; ++e) sh[qi * 40 + part * 10 + e] = ms[e];
    __syncthreads();
    if (threadIdx.x < 64) {
        const int qq = blockIdx.x * 64 + threadIdx.x;
        float fs[KTOP];
#pragma unroll
        for (int e = 0; e < KTOP; ++e) fs[e] = INFINITY;
        for (int x = 0; x < 40; ++x) {
            float v = sh[threadIdx.x * 40 + x];
            if (v < fs[9]) insert10s(v, fs);
        }
        tau[qq] = fs[9] + DELTA;
    }
}

// ---------- list build: per-seg qualifying queries + flat work queue ----------
// Seg s can emit for query q iff min(minbuf[2s][q], minbuf[2s+1][q]) <= tau[q]; exact
// equivalence with pass-2's emission test (same acc values, *-2 / *0.5 are exact).
__global__ void list_build(const float* __restrict__ minbuf, const float* __restrict__ tau,
                           int* __restrict__ qlist, int* __restrict__ wq,
                           int* __restrict__ wq_n, int m) {
    __shared__ int lq[MQ];
    __shared__ int lcnt;
    const int s = blockIdx.x, tid = threadIdx.x;
    if (tid == 0) lcnt = 0;
    __syncthreads();
    const float* r0 = minbuf + (size_t)(2 * s) * m;
    const float* r1 = minbuf + (size_t)(2 * s + 1) * m;
    for (int q = tid; q < m; q += 256) {
        float v = fminf(r0[q], r1[q]);
        if (v <= tau[q]) { int p = atomicAdd(&lcnt, 1); lq[p] = q; }
    }
    __syncthreads();
    const int c = lcnt;
    const int padded = (c + 255) & ~255;
    for (int i = c + tid; i < padded; i += 256) lq[i] = -1;   // sentinel queries
    __syncthreads();
    for (int i = tid; i < padded; i += 256) qlist[(size_t)s * MQ + i] = lq[i];
    if (tid == 0 && c > 0) {
        const int nqc = padded >> 8;
        int base = atomicAdd(wq_n, nqc * NPART);
        for (int qc = 0; qc < nqc; ++qc)
            for (int p = 0; p < NPART; ++p)
                wq[base++] = (s << 6) | (qc << 3) | p;
    }
}

// ---------- pass 2: sparse candidate emission over the work queue ----------
__global__ __launch_bounds__(256, 4) void nd_pass2(
        const ushort* __restrict__ Xbp, const ushort* __restrict__ Xtb,
        const float* __restrict__ tau,
        int* __restrict__ cnt, int* __restrict__ buf,
        const int* __restrict__ qlist, const int* __restrict__ wq,
        const int* __restrict__ wq_n, int m) {
    __shared__ __align__(16) ushort As[2 * BUFU];

    const int t = threadIdx.x;
    const int l = t & 63, wv = t >> 6;
    const int half = l >> 5;
    const int halfx = half ^ ((l >> 2) & 1);
    const int u0 = t, u1 = 256 + t, u2 = 512 + (t & 63);
    const int L0 = lds_unit(u0) * 8, L1 = lds_unit(u1) * 8, L2 = lds_unit(u2) * 8;
    const uint4* Xg = (const uint4*)Xbp;
    const int T = wq_n[0];

    for (int w = blockIdx.x; w < T; w += gridDim.x) {
        const int it = wq[w];
        const int s = it >> 6, qc = (it >> 3) & 7, part = it & 7;
        const int t0 = s * NT + part * TPP;
        const int lbase = s * MQ + qc * 256 + wv * 64 + (l & 31);
        const int qi0 = qlist[lbase], qi1 = qlist[lbase + 32];
        const int q0e = qi0 < 0 ? 0 : qi0, q1e = qi1 < 0 ? 0 : qi1;

        short8 Bf[8][2];
#pragma unroll
        for (int sk = 0; sk < 8; ++sk) {
            Bf[sk][0] = *(const short8*)(Xtb + (size_t)q0e * D + sk * 16 + half * 8);
            Bf[sk][1] = *(const short8*)(Xtb + (size_t)q1e * D + sk * 16 + half * 8);
        }
        short8 B8 = (short8)(short)0;
        if (l < 32) { B8[0] = (short)0xBF00; B8[1] = (short)0xBF00; }
        const float tp0 = (qi0 < 0) ? INFINITY : (-0.5f * tau[qi0]);
        const float tp1 = (qi1 < 0) ? INFINITY : (-0.5f * tau[qi1]);

        uint4 r0 = Xg[(size_t)t0 * TUNITS + u0];
        uint4 r1 = Xg[(size_t)t0 * TUNITS + u1];
        uint4 r2 = make_uint4(0, 0, 0, 0);
        if (t < 64) r2 = Xg[(size_t)t0 * TUNITS + u2];

        for (int t2 = t0; t2 < t0 + TPP; ++t2) {
            ushort* Lb = &As[(t2 & 1) * BUFU];
            *(uint4*)&Lb[L0] = r0;
            *(uint4*)&Lb[L1] = r1;
            if (t < 64) *(uint4*)&Lb[L2] = r2;
            __syncthreads();

            const size_t gb = (size_t)(t2 + 1) * TUNITS;   // overrun covered by pad tiles
            r0 = Xg[gb + u0];
            r1 = Xg[gb + u1];
            if (t < 64) r2 = Xg[gb + u2];

            f32x16 acc0 = (f32x16)0.f, acc1 = (f32x16)0.f;
#pragma unroll
            for (int ks = 0; ks < 9; ++ks) {
                const int kb = (ks < 8) ? (ks * 2 + halfx) : (16 + halfx);
                short8 a = *(const short8*)&Lb[((l & 31) * 18 + kb) * 8];
                short8 b0 = (ks < 8) ? Bf[ks][0] : B8;
                short8 b1 = (ks < 8) ? Bf[ks][1] : B8;
                acc0 = __builtin_amdgcn_mfma_f32_32x32x16_bf16(a, b0, acc0, 0, 0, 0);
                acc1 = __builtin_amdgcn_mfma_f32_32x32x16_bf16(a, b1, acc1, 0, 0, 0);
            }

            float h0 = -INFINITY, h1 = -INFINITY;
#pragma unroll
            for (int r = 0; r < 16; ++r) { h0 = fmaxf(h0, acc0[r]); h1 = fmaxf(h1, acc1[r]); }
            const int base = t2 * TILE_C;
            if (__any(h0 >= tp0)) {
#pragma unroll
                for (int r = 0; r < 16; ++r)
                    if (acc0[r] >= tp0) emit_cand(qi0, base + (r & 3) + 8 * (r >> 2) + 4 * half, cnt, buf);
            }
            if (__any(h1 >= tp1)) {
#pragma unroll
                for (int r = 0; r < 16; ++r)
                    if (acc1[r] >= tp1) emit_cand(qi1, base + (r & 3) + 8 * (r >> 2) + 4 * half, cnt, buf);
            }
        }
        __syncthreads();   // item boundary: next item's first LDS write vs this item's last reads
    }
}

// ---------- exact fp32 rescore ----------
__global__ void rescore_kernel(const float* __restrict__ Xtf, const float* __restrict__ Xf,
                               const float* __restrict__ w, const float* __restrict__ x2wf,
                               const float* __restrict__ q2f, const int* __restrict__ cnt,
                               const int* __restrict__ buf, float* __restrict__ out, int m) {
    __shared__ float sS[CAP], sW[CAP];
    const int q = blockIdx.x, l = threadIdx.x;
    const int c = min(cnt[q], CAP);
    const bool v0 = l < c, v1 = l + 64 < c;
    const int j0 = v0 ? buf[q * CAP + l] : 0;
    const int j1 = v1 ? buf[q * CAP + l + 64] : 0;
    const float4* Q4 = (const float4*)Xtf + (size_t)q * 32;
    const float4* A4 = (const float4*)Xf + (size_t)j0 * 32;
    const float4* B4 = (const float4*)Xf + (size_t)j1 * 32;
    float acc0 = 0.f, acc1 = 0.f;
#pragma unroll 8
    for (int d = 0; d < 32; ++d) {
        float4 qv = Q4[d];
        float4 a = A4[d], b = B4[d];
        acc0 = fmaf(qv.x, a.x, fmaf(qv.y, a.y, fmaf(qv.z, a.z, fmaf(qv.w, a.w, acc0))));
        acc1 = fmaf(qv.x, b.x, fmaf(qv.y, b.y, fmaf(qv.z, b.z, fmaf(qv.w, b.w, acc1))));
    }
    sS[l]      = v0 ? (x2wf[j0] - 2.f * acc0) : INFINITY;
    sW[l]      = v0 ? w[j0] : 0.f;
    sS[l + 64] = v1 ? (x2wf[j1] - 2.f * acc1) : INFINITY;
    sW[l + 64] = v1 ? w[j1] : 0.f;
    __syncthreads();
    if (l == 0) {
        float ls[KTOP], lw[KTOP];
#pragma unroll
        for (int e = 0; e < KTOP; ++e) { ls[e] = INFINITY; lw[e] = 0.f; }
        for (int i = 0; i < c; ++i)
            if (sS[i] < ls[9]) insert10(sS[i], sW[i], ls, lw);
        float q2v = q2f[q];
        float mxv = -INFINITY;
#pragma unroll
        for (int e = 0; e < KTOP; ++e) {
            if (ls[e] < 1e30f) {
                float d2 = fmaxf(q2v + ls[e] + lw[e], 0.f);
                mxv = fmaxf(mxv, lw[e] - sqrtf(d2));
            }
        }
        out[q] = mxv;
    }
}

// ---------- launch ----------
extern "C" void kernel_launch(void* const* d_in, const int* in_sizes, int n_in,
                              void* d_out, int out_size, void* d_ws, size_t ws_size,
                              hipStream_t stream) {
    const float* Xt = (const float*)d_in[0];
    const float* X  = (const float*)d_in[1];
    const float* w  = (const float*)d_in[2];
    const int m = in_sizes[0] / D;   // 2048
    const int n = in_sizes[1] / D;   // 100000

    auto align256 = [](size_t x) { return (x + 255) & ~(size_t)255; };
    char* p = (char*)d_ws;
    ushort* Xbp  = (ushort*)p;  p += align256((size_t)NPAD * ROWU * 2);     // ~29.5 MB
    ushort* Xtb  = (ushort*)p;  p += align256((size_t)m * D * 2);
    float*  x2wf = (float*)p;   p += align256((size_t)n * 4);
    float*  q2f  = (float*)p;   p += align256((size_t)m * 4);
    float*  minb = (float*)p;   p += align256((size_t)2 * NSEG * m * 4);    // 2 MB
    float*  tau  = (float*)p;   p += align256((size_t)m * 4);
    int*    cnt  = (int*)p;     p += align256((size_t)m * 4);
    int*    buf  = (int*)p;     p += align256((size_t)m * CAP * 4);
    int*    qlist= (int*)p;     p += align256((size_t)NSEG * MQ * 4);       // 1 MB
    int*    wq   = (int*)p;     p += align256((size_t)WQCAP * 4);
    int*    wq_n = (int*)p;     p += align256((size_t)256);

    const int nblocksA = (NPAD + 3) / 4;
    const int nblocksB = (m + 3) / 4;
    prep_kernel<<<nblocksA + nblocksB, 256, 0, stream>>>(Xt, X, w, Xbp, Xtb, x2wf, q2f,
                                                         cnt, wq_n, n, m, nblocksA);

    dim3 grid1(NSEG, m / 256);
    nd_pass1<<<grid1, 256, 0, stream>>>(Xbp, Xtb, minb, m);
    tau_kernel<<<m / 64, 256, 0, stream>>>(minb, tau, m);
    list_build<<<NSEG, 256, 0, stream>>>(minb, tau, qlist, wq, wq_n, m);
    nd_pass2<<<1024, 256, 0, stream>>>(Xbp, Xtb, tau, cnt, buf, qlist, wq, wq_n, m);
    rescore_kernel<<<m, 64, 0, stream>>>(Xt, X, w, x2wf, q2f, cnt, buf, (float*)d_out, m);
}